// Round 9
// baseline (34.773 us; speedup 1.0000x reference)
//
#include <hip/hip_runtime.h>
#include <math.h>

#define HS 64
#define WS 208
#define HF 128
#define WF 416
#define NS (HS * WS)   // 13312
#define KH 20
#define KS 41
#define KK (KS * KS)   // 1681
#define NJ2 7          // ceil(1681/256); last iter: tid<145 live
#define PPB 8          // pixels per block; 208/8 = 26 blocks per image row

// align_corners grid: f32 coords exactly as _resize_ac (arange(f32) * (f32(in-1)/f32(out-1))).
__device__ __forceinline__ void ac_idx(int o, int inN, float sc, int& i0, int& i1, float& w) {
#pragma clang fp contract(off)
    float s = (float)o * sc;
    float f = floorf(s);
    i0 = (int)f;
    i1 = min(i0 + 1, inN - 1);
    w = s - f;
}

// k_down: bit-faithful f32 resize of R -> ray4 (padded float4 triples) and of X ->
// normalized dir4; thread 0 also computes the f32 temperature.
__global__ void k_down(const float* __restrict__ R, const float* __restrict__ X,
                       const int* __restrict__ prog,
                       float4* __restrict__ ray4, float4* __restrict__ dir4,
                       float* __restrict__ tbuf) {
#pragma clang fp contract(off)
    int n = blockIdx.x * blockDim.x + threadIdx.x;
    if (n >= NS) return;
    if (n == 0) {
        double T64 = fmax(1e-8, 1e-4 / exp(0.1 * (double)prog[0]));
        tbuf[0] = (float)T64;   // same bits as np.float32(max(1e-8, 1e-4/exp(...)))
    }
    int y = n / WS, x = n - y * WS;
    int y0, y1, x0, x1; float wy, wx;
    ac_idx(y, HF, 127.0f / 63.0f, y0, y1, wy);
    ac_idx(x, WF, 415.0f / 207.0f, x0, x1, wx);
    float omwy = 1.0f - wy, omwx = 1.0f - wx;
    float r[3], d[3];
#pragma unroll
    for (int c = 0; c < 3; ++c) {
        const float* p = R + c * (HF * WF);
        float v00 = p[y0 * WF + x0], v10 = p[y1 * WF + x0];
        float v01 = p[y0 * WF + x1], v11 = p[y1 * WF + x1];
        float a0 = v00 * omwy; float b0 = v10 * wy; float t0 = a0 + b0;
        float a1 = v01 * omwy; float b1 = v11 * wy; float t1 = a1 + b1;
        float c0 = t0 * omwx; float c1 = t1 * wx;
        r[c] = c0 + c1;
        const float* q = X + c * (HF * WF);
        float u00 = q[y0 * WF + x0], u10 = q[y1 * WF + x0];
        float u01 = q[y0 * WF + x1], u11 = q[y1 * WF + x1];
        float e0 = u00 * omwy; float f0 = u10 * wy; float s0 = e0 + f0;
        float e1 = u01 * omwy; float f1 = u11 * wy; float s1 = e1 + f1;
        float g0 = s0 * omwx; float g1 = s1 * wx;
        d[c] = g0 + g1;
    }
    float q0 = d[0] * d[0]; float q1 = d[1] * d[1]; float q2 = d[2] * d[2];
    float ssq = (q0 + q1) + q2;
    float nrm = (float)sqrt((double)ssq);   // correctly-rounded f32 sqrt
    ray4[n] = make_float4(r[0], r[1], r[2], 0.0f);
    dir4[n] = make_float4(d[0] / nrm, d[1] / nrm, d[2] / nrm, 0.0f);
}

// One BLOCK (256 threads) per PPB horizontally-consecutive pixels (same image row).
// The 41x41 window slides one column per pixel -> pixels 2..PPB hit L1 for ~40/41 of
// their reads (L2 traffic /8). Per-pixel body identical to the round-7 structure.
__global__ __launch_bounds__(256) void k_main(const float4* __restrict__ ray4,
                                              const float4* __restrict__ dir4,
                                              const float* __restrict__ tbuf,
                                              float* __restrict__ xn, float* __restrict__ yn) {
#pragma clang fp contract(off)
    int pix0 = blockIdx.x * PPB;
    int tid = (int)threadIdx.x;
    int lane = tid & 63;
    int wid = tid >> 6;
    int h = pix0 / WS, w0 = pix0 - h * WS;       // all PPB pixels share the row h
    int srow = min(max(h - KH, 0), HS - 1 - 2 * KH);

    float Tf = tbuf[0];
    int k1i = (tid * 25) >> 10;        // exact floor(tid/41) for tid<256
    int k2i = tid - k1i * KS;

    __shared__ float smax[4];
    __shared__ float ssum[4][3];

    for (int i = 0; i < PPB; ++i) {
        int pix = pix0 + i;
        int w = w0 + i;
        int scol = min(max(w - KH, 0), WS - 1 - 2 * KH);

        float4 dv = dir4[pix];
        float d0 = dv.x, d1 = dv.y, d2 = dv.z;

        int off = (srow + k1i) * WS + scol + k2i;
        int colk = k2i;

        // Pass 1: raw logits, bit-exact ((p0+p1)+p2), running max. k += 256 = 6*41+10.
        float lg[NJ2];
        float m = -INFINITY;
#pragma unroll
        for (int j = 0; j < NJ2 - 1; ++j) {
            float4 v = ray4[off];
            float p0 = d0 * v.x; float p1 = d1 * v.y; float p2 = d2 * v.z;
            float l = (p0 + p1) + p2;
            lg[j] = l;
            m = fmaxf(m, l);
            int cn = colk + 10;
            bool cr = cn >= KS;
            colk = cr ? cn - KS : cn;
            off += cr ? (7 * WS - 31) : (6 * WS + 10);
        }
        {   // j=6: k = tid + 1536, live iff tid < 145
            float l = -INFINITY;
            if (tid < KK - 256 * (NJ2 - 1)) {
                float4 v = ray4[off];
                float p0 = d0 * v.x; float p1 = d1 * v.y; float p2 = d2 * v.z;
                l = (p0 + p1) + p2;
            }
            lg[NJ2 - 1] = l;
            m = fmaxf(m, l);
        }
#pragma unroll
        for (int s = 1; s < 64; s <<= 1) m = fmaxf(m, __shfl_xor(m, s));

        if (lane == 0) smax[wid] = m;
        __syncthreads();
        m = fmaxf(fmaxf(smax[0], smax[1]), fmaxf(smax[2], smax[3]));

        float zm = m / Tf;             // monotone div: == ref's max-of-(l/T)
        float thresh = m - 0.004f;     // below: z-zm < -108 -> f32 weight exactly 0

        // Pass 2: incremental (k1,k2) replay; only live-ballot iterations pay div+exp.
        float se = 0.f, sr = 0.f, sc = 0.f;
        int c1 = k1i, c2 = k2i;
#pragma unroll
        for (int j = 0; j < NJ2; ++j) {
            bool a = lg[j] > thresh;   // dead lanes hold -INF -> false
            if (__ballot(a)) {
                float z = lg[j] / Tf;  // bit-identical to ref's logits/T
                float arg = (z - zm) * 1.442695040888963f;
                float e = a ? __builtin_amdgcn_exp2f(arg) : 0.0f;
                se += e;
                sr += e * (float)(srow + c1);
                sc += e * (float)(scol + c2);
            }
            int cn = c2 + 10;
            bool cr = cn >= KS;
            c2 = cr ? cn - KS : cn;
            c1 += cr ? 7 : 6;
        }
#pragma unroll
        for (int s = 1; s < 64; s <<= 1) {
            se += __shfl_xor(se, s);
            sr += __shfl_xor(sr, s);
            sc += __shfl_xor(sc, s);
        }
        if (lane == 0) { ssum[wid][0] = se; ssum[wid][1] = sr; ssum[wid][2] = sc; }
        __syncthreads();
        if (tid == 0) {
            float SE = (ssum[0][0] + ssum[1][0]) + (ssum[2][0] + ssum[3][0]);
            float SR = (ssum[0][1] + ssum[1][1]) + (ssum[2][1] + ssum[3][1]);
            float SC = (ssum[0][2] + ssum[1][2]) + (ssum[2][2] + ssum[3][2]);
            double ix = (double)SR / (double)SE, iy = (double)SC / (double)SE;
            xn[pix] = (float)(2.0 * ix / (double)(HS - 1) - 1.0);
            yn[pix] = (float)(2.0 * iy / (double)(WS - 1) - 1.0);
        }
        // barrier2 (the ssum __syncthreads above) separates this pixel's smax reads
        // from the next pixel's smax writes -> race-free reuse of the LDS scratch.
    }
}

// Bilinear upsample (align_corners) of (Yn, Xn) to full res, interleaved channels.
__global__ void k_up(const float* __restrict__ xn, const float* __restrict__ yn,
                     float* __restrict__ out) {
#pragma clang fp contract(off)
    int i = blockIdx.x * blockDim.x + threadIdx.x;
    if (i >= HF * WF) return;
    int hh = i / WF, ww = i - hh * WF;
    int y0, y1, x0, x1; float wy, wx;
    ac_idx(hh, HS, 63.0f / 127.0f, y0, y1, wy);
    ac_idx(ww, WS, 207.0f / 415.0f, x0, x1, wx);
    float omwy = 1.0f - wy, omwx = 1.0f - wx;
    float a0, b0, t0, t1;
    a0 = xn[y0 * WS + x0] * omwy; b0 = xn[y1 * WS + x0] * wy; t0 = a0 + b0;
    a0 = xn[y0 * WS + x1] * omwy; b0 = xn[y1 * WS + x1] * wy; t1 = a0 + b0;
    float bx = t0 * omwx + t1 * wx;     // Xn upsampled
    a0 = yn[y0 * WS + x0] * omwy; b0 = yn[y1 * WS + x0] * wy; t0 = a0 + b0;
    a0 = yn[y0 * WS + x1] * omwy; b0 = yn[y1 * WS + x1] * wy; t1 = a0 + b0;
    float ay = t0 * omwx + t1 * wx;     // Yn upsampled
    out[2 * i]     = ay;
    out[2 * i + 1] = bx;
}

extern "C" void kernel_launch(void* const* d_in, const int* in_sizes, int n_in,
                              void* d_out, int out_size, void* d_ws, size_t ws_size,
                              hipStream_t stream) {
    const float* R = (const float*)d_in[0];
    const float* X = (const float*)d_in[1];
    const int* prog = (const int*)d_in[2];
    float4* ray4 = (float4*)d_ws;            // NS float4
    float4* dir4 = ray4 + NS;                // NS float4
    float* xn   = (float*)(dir4 + NS);       // NS
    float* yn   = xn + NS;                   // NS
    float* tbuf = yn + NS;                   // 1
    float* out  = (float*)d_out;

    k_down<<<(NS + 255) / 256, 256, 0, stream>>>(R, X, prog, ray4, dir4, tbuf);
    k_main<<<NS / PPB, 256, 0, stream>>>(ray4, dir4, tbuf, xn, yn);  // block per 8 px
    k_up<<<(HF * WF + 255) / 256, 256, 0, stream>>>(xn, yn, out);
}

// Round 10
// 28.082 us; speedup vs baseline: 1.2383x; 1.2383x over previous
//
#include <hip/hip_runtime.h>
#include <math.h>

#define HS 64
#define WS 208
#define HF 128
#define WF 416
#define NS (HS * WS)   // 13312
#define KH 20
#define KS 41
#define KK (KS * KS)   // 1681
#define TW 8           // tile width in pixels
#define TH 8           // tile height in pixels
#define NBX (WS / TW)  // 26
#define NBY (HS / TH)  // 8
#define NBLK (NBX * NBY) // 208
#define TDIM 48        // union window side (8-1 + 41)
#define LOG2E 1.442695040888963f

// align_corners grid: f32 coords exactly as _resize_ac (arange(f32) * (f32(in-1)/f32(out-1))).
__device__ __forceinline__ void ac_idx(int o, int inN, float sc, int& i0, int& i1, float& w) {
#pragma clang fp contract(off)
    float s = (float)o * sc;
    float f = floorf(s);
    i0 = (int)f;
    i1 = min(i0 + 1, inN - 1);
    w = s - f;
}

// Fused kernel: one block per 8x8 pixel tile. Stages the 48x48 union ray-window in
// LDS (bit-exact k_down math recomputed per element), computes 64 directions, then
// 8 slice-threads per pixel do the sharp softmax + soft-argmax.
__global__ __launch_bounds__(512, 1) void k_fused(const float* __restrict__ R,
                                                  const float* __restrict__ X,
                                                  const int* __restrict__ prog,
                                                  float* __restrict__ xn,
                                                  float* __restrict__ yn) {
#pragma clang fp contract(off)
    __shared__ float4 tile[TDIM * TDIM];   // XOR-swizzled: [i][j ^ (i&7)]
    __shared__ float4 dirs[64];
    __shared__ float smax_l[8][64];
    __shared__ float ssum_l[3][8][64];
    __shared__ float Tsh;

    int t = (int)threadIdx.x;
    int blk = (int)blockIdx.x;
    int by = blk / NBX, bx = blk - by * NBX;
    int ph0 = by * TH, pw0 = bx * TW;
    int srow_min = min(max(ph0 - KH, 0), HS - 1 - 2 * KH);
    int scol_min = min(max(pw0 - KH, 0), WS - 1 - 2 * KH);

    // ---- stage ray tile (bit-exact f32 resize of R, mul/mul/add, no FMA) ----
    for (int e = t; e < TDIM * TDIM; e += 512) {
        int i = e / TDIM, j = e - i * TDIM;
        int g = srow_min + i, cg = scol_min + j;
        if (g < HS && cg < WS) {
            int y0, y1, x0, x1; float wy, wx;
            ac_idx(g, HF, 127.0f / 63.0f, y0, y1, wy);
            ac_idx(cg, WF, 415.0f / 207.0f, x0, x1, wx);
            float omwy = 1.0f - wy, omwx = 1.0f - wx;
            float r[3];
#pragma unroll
            for (int c = 0; c < 3; ++c) {
                const float* p = R + c * (HF * WF);
                float v00 = p[y0 * WF + x0], v10 = p[y1 * WF + x0];
                float v01 = p[y0 * WF + x1], v11 = p[y1 * WF + x1];
                float a0 = v00 * omwy; float b0 = v10 * wy; float t0 = a0 + b0;
                float a1 = v01 * omwy; float b1 = v11 * wy; float t1 = a1 + b1;
                float c0 = t0 * omwx; float c1 = t1 * wx;
                r[c] = c0 + c1;
            }
            tile[i * TDIM + (j ^ (i & 7))] = make_float4(r[0], r[1], r[2], 0.0f);
        }
    }
    // ---- directions for the 64 tile pixels (bit-exact resize of X + normalize) ----
    if (t < 64) {
        int py = t >> 3, px = t & 7;
        int h = ph0 + py, w = pw0 + px;
        int y0, y1, x0, x1; float wy, wx;
        ac_idx(h, HF, 127.0f / 63.0f, y0, y1, wy);
        ac_idx(w, WF, 415.0f / 207.0f, x0, x1, wx);
        float omwy = 1.0f - wy, omwx = 1.0f - wx;
        float d[3];
#pragma unroll
        for (int c = 0; c < 3; ++c) {
            const float* q = X + c * (HF * WF);
            float u00 = q[y0 * WF + x0], u10 = q[y1 * WF + x0];
            float u01 = q[y0 * WF + x1], u11 = q[y1 * WF + x1];
            float e0 = u00 * omwy; float f0 = u10 * wy; float s0 = e0 + f0;
            float e1 = u01 * omwy; float f1 = u11 * wy; float s1 = e1 + f1;
            float g0 = s0 * omwx; float g1 = s1 * wx;
            d[c] = g0 + g1;
        }
        float q0 = d[0] * d[0]; float q1 = d[1] * d[1]; float q2 = d[2] * d[2];
        float ssq = (q0 + q1) + q2;
        float nrm = (float)sqrt((double)ssq);   // correctly-rounded f32 sqrt
        dirs[t] = make_float4(d[0] / nrm, d[1] / nrm, d[2] / nrm, 0.0f);
    }
    if (t == 0) {
        double T64 = fmax(1e-8, 1e-4 / exp(0.1 * (double)prog[0]));
        Tsh = (float)T64;   // same bits as np.float32(max(1e-8, 1e-4/exp(...)))
    }
    __syncthreads();

    // ---- per-thread setup: pixel p, slice s (s is wave-uniform: s = t>>6) ----
    int p = t & 63, s = t >> 6;
    int py = p >> 3, px = p & 7;
    int h = ph0 + py, w = pw0 + px;
    int srow = min(max(h - KH, 0), HS - 1 - 2 * KH);
    int scol = min(max(w - KH, 0), WS - 1 - 2 * KH);
    int I0 = srow - srow_min;          // 0..7
    int J0 = scol - scol_min;          // 0..7
    float4 dv = dirs[p];
    float d0 = dv.x, d1 = dv.y, d2 = dv.z;
    float Tf = Tsh;

    // ---- pass 1: slice rows r = s + 8q; bit-exact logits, running max,
    //      survivor bitmask (flag = l > m_run - 0.004, superset of final survivors) ----
    float m = -INFINITY;
    unsigned mask[8] = {0u, 0u, 0u, 0u, 0u, 0u, 0u, 0u};
#pragma unroll
    for (int q = 0; q < 5; ++q) {
        int r = s + 8 * q;
        int I = I0 + r;
        int rowb = I * TDIM;
        int ib = I & 7;
#pragma unroll
        for (int c = 0; c < KS; ++c) {
            float4 v = tile[rowb + ((J0 + c) ^ ib)];
            float p0 = d0 * v.x; float p1 = d1 * v.y; float p2 = d2 * v.z;
            float l = (p0 + p1) + p2;
            int ei = q * KS + c;
            bool f = l > (m - 0.004f);
            mask[ei >> 5] |= f ? (1u << (ei & 31)) : 0u;
            m = fmaxf(m, l);
        }
    }
    if (s == 0) {   // wave-uniform branch: slice 0 owns the 6th row (r = 40)
        int I = I0 + 40;
        int rowb = I * TDIM;
        int ib = I & 7;
#pragma unroll
        for (int c = 0; c < KS; ++c) {
            float4 v = tile[rowb + ((J0 + c) ^ ib)];
            float p0 = d0 * v.x; float p1 = d1 * v.y; float p2 = d2 * v.z;
            float l = (p0 + p1) + p2;
            int ei = 5 * KS + c;
            bool f = l > (m - 0.004f);
            mask[ei >> 5] |= f ? (1u << (ei & 31)) : 0u;
            m = fmaxf(m, l);
        }
    }

    // ---- max reduce across the 8 slices of each pixel ----
    smax_l[s][p] = m;
    __syncthreads();
    float mf = smax_l[0][p];
#pragma unroll
    for (int s2 = 1; s2 < 8; ++s2) mf = fmaxf(mf, smax_l[s2][p]);

    float zm = mf / Tf;                // monotone div: == ref's max-of-(l/T)
    float thresh = mf - 0.004f;        // below: z-zm < -108 -> f32 weight exactly 0

    // ---- pass 2: revisit flagged elements only; exact IEEE div + exp2 ----
    float se = 0.f, sr = 0.f, sc = 0.f;
#pragma unroll
    for (int u = 0; u < 8; ++u) {
        unsigned w8 = mask[u];
        while (w8) {
            int b = __ffs(w8) - 1;
            w8 &= w8 - 1;
            int ei = u * 32 + b;
            int q = (ei * 25) >> 10;   // exact floor(ei/41) for ei<256
            int c = ei - q * KS;
            int r = s + 8 * q;
            int I = I0 + r;
            float4 v = tile[I * TDIM + ((J0 + c) ^ (I & 7))];
            float p0 = d0 * v.x; float p1 = d1 * v.y; float p2 = d2 * v.z;
            float l = (p0 + p1) + p2;
            if (l > thresh) {
                float z = l / Tf;      // bit-identical to ref's logits/T
                float e2 = __builtin_amdgcn_exp2f((z - zm) * LOG2E);
                se += e2;
                sr += e2 * (float)(srow + r);
                sc += e2 * (float)(scol + c);
            }
        }
    }
    ssum_l[0][s][p] = se; ssum_l[1][s][p] = sr; ssum_l[2][s][p] = sc;
    __syncthreads();
    if (t < 64) {
        float SE = 0.f, SR = 0.f, SC = 0.f;
#pragma unroll
        for (int s2 = 0; s2 < 8; ++s2) {
            SE += ssum_l[0][s2][t];
            SR += ssum_l[1][s2][t];
            SC += ssum_l[2][s2][t];
        }
        int pix = (ph0 + (t >> 3)) * WS + (pw0 + (t & 7));
        double ix = (double)SR / (double)SE, iy = (double)SC / (double)SE;
        xn[pix] = (float)(2.0 * ix / (double)(HS - 1) - 1.0);
        yn[pix] = (float)(2.0 * iy / (double)(WS - 1) - 1.0);
    }
}

// Bilinear upsample (align_corners) of (Yn, Xn) to full res, interleaved channels.
__global__ void k_up(const float* __restrict__ xn, const float* __restrict__ yn,
                     float* __restrict__ out) {
#pragma clang fp contract(off)
    int i = blockIdx.x * blockDim.x + threadIdx.x;
    if (i >= HF * WF) return;
    int hh = i / WF, ww = i - hh * WF;
    int y0, y1, x0, x1; float wy, wx;
    ac_idx(hh, HS, 63.0f / 127.0f, y0, y1, wy);
    ac_idx(ww, WS, 207.0f / 415.0f, x0, x1, wx);
    float omwy = 1.0f - wy, omwx = 1.0f - wx;
    float a0, b0, t0, t1;
    a0 = xn[y0 * WS + x0] * omwy; b0 = xn[y1 * WS + x0] * wy; t0 = a0 + b0;
    a0 = xn[y0 * WS + x1] * omwy; b0 = xn[y1 * WS + x1] * wy; t1 = a0 + b0;
    float bx = t0 * omwx + t1 * wx;     // Xn upsampled
    a0 = yn[y0 * WS + x0] * omwy; b0 = yn[y1 * WS + x0] * wy; t0 = a0 + b0;
    a0 = yn[y0 * WS + x1] * omwy; b0 = yn[y1 * WS + x1] * wy; t1 = a0 + b0;
    float ay = t0 * omwx + t1 * wx;     // Yn upsampled
    out[2 * i]     = ay;
    out[2 * i + 1] = bx;
}

extern "C" void kernel_launch(void* const* d_in, const int* in_sizes, int n_in,
                              void* d_out, int out_size, void* d_ws, size_t ws_size,
                              hipStream_t stream) {
    const float* R = (const float*)d_in[0];
    const float* X = (const float*)d_in[1];
    const int* prog = (const int*)d_in[2];
    float* xn = (float*)d_ws;        // NS
    float* yn = xn + NS;             // NS
    float* out = (float*)d_out;

    k_fused<<<NBLK, 512, 0, stream>>>(R, X, prog, xn, yn);
    k_up<<<(HF * WF + 255) / 256, 256, 0, stream>>>(xn, yn, out);
}